// Round 15
// baseline (4333.266 us; speedup 1.0000x reference)
//
#include <hip/hip_runtime.h>
#include <stdint.h>

// Problem constants
#define UNITS 512
#define EMB   512
#define SEQ   512
#define BATCH 64

// ws layout (bytes) — total need ~50 MiB (was 164 MiB; suspected ws overflow)
#define OFF_H0   0ull                      // h buffer 0 bf16 [64][512] : 64 KiB
#define OFF_H1   65536ull                  // h buffer 1                : 64 KiB
#define OFF_CNT  131072ull                 // barrier counter
#define OFF_EMB  (1ull<<20)                // emb bf16 [50000][512]     : 51.2 MB
#define WS_NEED  (OFF_EMB + 50000ull*512ull*2ull)

typedef __attribute__((ext_vector_type(4))) float  f4;
typedef __attribute__((ext_vector_type(8))) short  s8v;
typedef __attribute__((ext_vector_type(4))) short  s4v;

__device__ __forceinline__ unsigned short f2bf(float f) {
  unsigned u = __float_as_uint(f);
  return (unsigned short)((u + 0x7fffu + ((u >> 16) & 1u)) >> 16);
}
__device__ __forceinline__ float bf2f(unsigned short h) {
  return __uint_as_float(((unsigned)h) << 16);
}
__device__ __forceinline__ s8v pack8(f4 a, f4 b) {
  s8v o;
  o[0] = (short)f2bf(a[0]); o[1] = (short)f2bf(a[1]);
  o[2] = (short)f2bf(a[2]); o[3] = (short)f2bf(a[3]);
  o[4] = (short)f2bf(b[0]); o[5] = (short)f2bf(b[1]);
  o[6] = (short)f2bf(b[2]); o[7] = (short)f2bf(b[3]);
  return o;
}
// async 16B global -> LDS (LDS dest = wave-uniform base + lane*16; global src per-lane)
__device__ __forceinline__ void async16(void* lds, const void* g) {
  __builtin_amdgcn_global_load_lds(
      (const __attribute__((address_space(1))) unsigned int*)g,
      (__attribute__((address_space(3))) unsigned int*)lds, 16, 0, 0);
}

// -------- sentinel: ws too small — write -1 so the bench reports absmax~1.1 -------
__global__ void sentinel_kernel(float* __restrict__ out, int n) {
  int gid = blockIdx.x * 256 + threadIdx.x;
  if (gid < n) out[gid] = -1.0f;
}

// -------- prep: emb fp32 -> bf16, zero h buffers + barrier counter ----------------
__global__ void prep_kernel(const float* __restrict__ emb, unsigned short* __restrict__ embB,
                            unsigned short* __restrict__ hzero, unsigned* __restrict__ cnt) {
  int gid = blockIdx.x * 256 + threadIdx.x;   // 25000 blocks = 6,400,000 threads exact
  f4 v0 = ((const f4*)emb)[gid];
  s4v o;
  o[0] = (short)f2bf(v0[0]); o[1] = (short)f2bf(v0[1]);
  o[2] = (short)f2bf(v0[2]); o[3] = (short)f2bf(v0[3]);
  ((s4v*)embB)[gid] = o;
  if (gid < 16384) ((unsigned long long*)hzero)[gid] = 0ull;  // zero h0+h1 (128 KiB)
  if (gid == 0) *cnt = 0u;
}

// -------- persistent LSTM recurrence (fused x·W + h·U) ----------------------------
// 32 WGs x 256 threads. WG j owns units [j*16, j*16+16) for all 4 gates, all 64 batches.
// Wave w == gate w; holds W-slice AND U-slice (16 units x 512) as bf16 frags in regs.
// Per step: stage h(prev) and x(t) (64x512 bf16 each) into LDS via global_load_lds
// with XOR-pre-swizzled sources; 128 MFMA/wave; activations; global barrier.
__global__ __launch_bounds__(256) void lstm_recurrence(
    const float* __restrict__ Wg, const float* __restrict__ Uw,
    const int* __restrict__ sent, const unsigned short* __restrict__ embB,
    unsigned short* __restrict__ h0, unsigned short* __restrict__ h1,
    unsigned* __restrict__ cnt) {
  __shared__ unsigned short h_lds[64 * 512];   // 64 KiB
  __shared__ unsigned short x_lds[64 * 512];   // 64 KiB; pre_lds aliases this after MFMAs
  float* pre_lds = (float*)x_lds;              // [4][16][64] fp32 = 16 KiB
  int j = blockIdx.x;
  int tid = threadIdx.x, w = tid >> 6, lane = tid & 63;

  // preload U and W fragments: wave w = gate w, rows = units j*16 + (lane&15)
  s8v uf[16], wf[16];
  {
    const float* up = Uw + (size_t)w * (512 * 512) + (size_t)(j * 16 + (lane & 15)) * 512;
    const float* wp = Wg + (size_t)w * (512 * 512) + (size_t)(j * 16 + (lane & 15)) * 512;
#pragma unroll
    for (int ks = 0; ks < 16; ++ks) {
      int k0 = ks * 32 + (lane >> 4) * 8;
      uf[ks] = pack8(*(const f4*)(up + k0), *(const f4*)(up + k0 + 4));
      wf[ks] = pack8(*(const f4*)(wp + k0), *(const f4*)(wp + k0 + 4));
    }
  }
  // cell-state ownership: thread owns batch b_own, 4 units u0..u0+3 (coalesced h store)
  int b_own = tid >> 2;        // 0..63
  int u0 = (tid & 3) * 4;      // 0,4,8,12 (local unit)
  float cst[4] = {0.f, 0.f, 0.f, 0.f};

#pragma unroll 1
  for (int t = 0; t < 512; ++t) {
    const unsigned short* hprev = (t & 1) ? h1 : h0;
    unsigned short* hnext = (t & 1) ? h0 : h1;
    // stage h and x: wave w stages rows r = it*4+w; lane covers chunk `lane`,
    // source chunk = lane ^ (r&7)  (linear LDS dest + inverse-swizzled source)
#pragma unroll
    for (int it = 0; it < 16; ++it) {
      int r = it * 4 + w;
      int cs = (lane ^ (r & 7)) * 8;
      int tok = sent[r * SEQ + t];
      async16(&h_lds[r * 512], hprev + (size_t)r * 512 + cs);
      async16(&x_lds[r * 512], embB + (size_t)tok * 512 + cs);
    }
    __syncthreads();
    // gates pre-activation: acc = U'·h + W'·x   (16 units x 64 batches, K=512 each)
    f4 acc[4] = {};
#pragma unroll
    for (int ks = 0; ks < 16; ++ks) {
#pragma unroll
      for (int bt = 0; bt < 4; ++bt) {
        int b = bt * 16 + (lane & 15);
        int ch = ((ks * 4 + (lane >> 4)) ^ (b & 7)) * 8;
        s8v hb = *(const s8v*)&h_lds[b * 512 + ch];
        acc[bt] = __builtin_amdgcn_mfma_f32_16x16x32_bf16(uf[ks], hb, acc[bt], 0, 0, 0);
      }
    }
#pragma unroll
    for (int ks = 0; ks < 16; ++ks) {
#pragma unroll
      for (int bt = 0; bt < 4; ++bt) {
        int b = bt * 16 + (lane & 15);
        int ch = ((ks * 4 + (lane >> 4)) ^ (b & 7)) * 8;
        s8v xb = *(const s8v*)&x_lds[b * 512 + ch];
        acc[bt] = __builtin_amdgcn_mfma_f32_16x16x32_bf16(wf[ks], xb, acc[bt], 0, 0, 0);
      }
    }
    __syncthreads();   // all waves done reading x_lds before pre_lds aliases it
    // write pre-activations [gate][u][b]
#pragma unroll
    for (int bt = 0; bt < 4; ++bt)
#pragma unroll
      for (int r = 0; r < 4; ++r)
        pre_lds[w * 1024 + ((lane >> 4) * 4 + r) * 64 + bt * 16 + (lane & 15)] = acc[bt][r];
    __syncthreads();
    // cell update: 4 owned cells (batch b_own, units u0..u0+3)
    float hv[4];
#pragma unroll
    for (int i = 0; i < 4; ++i) {
      int u = u0 + i;
      float p0 = pre_lds[0 * 1024 + u * 64 + b_own];
      float p1 = pre_lds[1 * 1024 + u * 64 + b_own];
      float p2 = pre_lds[2 * 1024 + u * 64 + b_own];
      float p3 = pre_lds[3 * 1024 + u * 64 + b_own];
      float ig = 1.f / (1.f + __expf(-p0));
      float fg = 1.f / (1.f + __expf(-p1));
      float og = 1.f / (1.f + __expf(-p2));
      float ng = tanhf(p3);
      float cn = fg * cst[i] + ig * ng;
      cst[i] = cn;
      hv[i] = og * tanhf(cn);
    }
    s4v hs;
    hs[0] = (short)f2bf(hv[0]); hs[1] = (short)f2bf(hv[1]);
    hs[2] = (short)f2bf(hv[2]); hs[3] = (short)f2bf(hv[3]);
    *(s4v*)(hnext + (size_t)b_own * 512 + j * 16 + u0) = hs;   // 8B coalesced
    __syncthreads();
    // device-scope barrier across 32 WGs; spin bounded (~0.5ms/step worst case —
    // converts any co-residency stall into a finishing, visibly-wrong run)
    if (tid == 0) {
      __hip_atomic_fetch_add(cnt, 1u, __ATOMIC_ACQ_REL, __HIP_MEMORY_SCOPE_AGENT);
      unsigned target = 32u * (unsigned)(t + 1);
      int guard = 20000;
      while (__hip_atomic_load(cnt, __ATOMIC_ACQUIRE, __HIP_MEMORY_SCOPE_AGENT) < target &&
             --guard > 0)
        __builtin_amdgcn_s_sleep(1);
    }
    __syncthreads();
  }
}

// -------- head: hidden = relu(h@W1+b1); logits = hidden@W2+b2; softmax ------------
__global__ void head_kernel(const unsigned short* __restrict__ h,
                            const float* __restrict__ W1, const float* __restrict__ b1,
                            const float* __restrict__ W2, const float* __restrict__ b2,
                            float* __restrict__ out) {
  __shared__ float hrow[512];
  __shared__ float hidden[32];
  __shared__ float logits[16];
  int b = blockIdx.x;       // 64 blocks
  int tid = threadIdx.x;    // 64 threads
  for (int k = tid; k < 512; k += 64) hrow[k] = bf2f(h[(size_t)b * 512 + k]);
  __syncthreads();
  if (tid < 32) {
    float s = b1[tid];
    for (int k = 0; k < 512; ++k) s += hrow[k] * W1[k * 32 + tid];
    hidden[tid] = s > 0.f ? s : 0.f;
  }
  __syncthreads();
  if (tid < 10) {
    float s = b2[tid];
    for (int k = 0; k < 32; ++k) s += hidden[k] * W2[k * 10 + tid];
    logits[tid] = s;
  }
  __syncthreads();
  if (tid == 0) {
    float mx = logits[0];
    for (int k = 1; k < 10; ++k) mx = fmaxf(mx, logits[k]);
    float e[10], sum = 0.f;
    for (int k = 0; k < 10; ++k) { e[k] = __expf(logits[k] - mx); sum += e[k]; }
    float inv = 1.f / sum;
    for (int k = 0; k < 10; ++k) out[b * 10 + k] = e[k] * inv;
  }
}

extern "C" void kernel_launch(void* const* d_in, const int* in_sizes, int n_in,
                              void* d_out, int out_size, void* d_ws, size_t ws_size,
                              hipStream_t stream) {
  const int*   sent = (const int*)d_in[0];
  const float* emb  = (const float*)d_in[1];
  const float* W    = (const float*)d_in[2];
  const float* U    = (const float*)d_in[3];
  const float* W1   = (const float*)d_in[4];
  const float* b1   = (const float*)d_in[5];
  const float* W2   = (const float*)d_in[6];
  const float* b2   = (const float*)d_in[7];
  float* out = (float*)d_out;

  if (ws_size < WS_NEED) {   // ws too small for this design: legible signature, no faults
    sentinel_kernel<<<(out_size + 255) / 256, 256, 0, stream>>>(out, out_size);
    return;
  }
  char* ws = (char*)d_ws;
  unsigned short* h0   = (unsigned short*)(ws + OFF_H0);
  unsigned short* h1   = (unsigned short*)(ws + OFF_H1);
  unsigned*       cnt  = (unsigned*)(ws + OFF_CNT);
  unsigned short* embB = (unsigned short*)(ws + OFF_EMB);

  prep_kernel<<<25000, 256, 0, stream>>>(emb, embB, h0, cnt);
  lstm_recurrence<<<32, 256, 0, stream>>>(W, U, sent, embB, h0, h1, cnt);
  head_kernel<<<64, 64, 0, stream>>>(h0, W1, b1, W2, b2, out);
}